// Round 11
// baseline (1819.929 us; speedup 1.0000x reference)
//
#include <hip/hip_runtime.h>
#include <math.h>

#define NSWEEPS 4

// Packed half2 storage for Jacobi columns. Rotation math f32, packed across
// the two slot matrices as float2.
// R9: parity-slot layout — odd-popcount rounds share the pair dot (bit-neutral).
// R10: ROLLED sweep loop (I$-resident ~7 KB body; R7's 60 KB fusion failure
// was I$ thrash). R11: glb + final fused into the tail of the same grid —
// glb's HBM re-read (~22 us) hides under SVD compute (1.5% HBM use);
// last-block ticket does the 4-float combine (R7-proven pattern).
typedef _Float16 f16x2 __attribute__((ext_vector_type(2)));
typedef float    f32x2 __attribute__((ext_vector_type(2)));

__device__ __forceinline__ int h2i(f16x2 v) { int r; __builtin_memcpy(&r, &v, 4); return r; }
__device__ __forceinline__ f16x2 i2h(int v) { f16x2 r; __builtin_memcpy(&r, &v, 4); return r; }
__device__ __forceinline__ f16x2 dup_h(float x) { _Float16 h = (_Float16)x; return f16x2{h, h}; }

__device__ __forceinline__ f32x2 rcp2(f32x2 v) {
  return f32x2{__builtin_amdgcn_rcpf(v.x), __builtin_amdgcn_rcpf(v.y)};
}
__device__ __forceinline__ f32x2 sqrt2(f32x2 v) {
  return f32x2{__builtin_amdgcn_sqrtf(v.x), __builtin_amdgcn_sqrtf(v.y)};
}
__device__ __forceinline__ f32x2 cpsgn2(f32x2 m, f32x2 s) {
  return f32x2{copysignf(m.x, s.x), copysignf(m.y, s.y)};  // v_bfi_b32 each
}

// XOR-exchange within 16-lane rows. DPP (VALU pipe) for R in {1,2,3,7,8,15};
// ds_swizzle BitMode (CU-shared LDS pipe) otherwise (pipe balance, R5-R8).
template<int R>
__device__ __forceinline__ int xexch_i(int iv) {
  if constexpr (R == 1)       return __builtin_amdgcn_update_dpp(iv, iv, 0x0B1, 0xF, 0xF, true);
  else if constexpr (R == 2)  return __builtin_amdgcn_update_dpp(iv, iv, 0x04E, 0xF, 0xF, true);
  else if constexpr (R == 3)  return __builtin_amdgcn_update_dpp(iv, iv, 0x01B, 0xF, 0xF, true);
  else if constexpr (R == 7)  return __builtin_amdgcn_update_dpp(iv, iv, 0x141, 0xF, 0xF, true);
  else if constexpr (R == 8)  return __builtin_amdgcn_update_dpp(iv, iv, 0x128, 0xF, 0xF, true);
  else if constexpr (R == 15) return __builtin_amdgcn_update_dpp(iv, iv, 0x140, 0xF, 0xF, true);
  else                        return __builtin_amdgcn_ds_swizzle(iv, (R << 10) | 0x1F);
}
template<int R>
__device__ __forceinline__ float xexch(float v) {
  return __int_as_float(xexch_i<R>(__float_as_int(v)));
}

// One parallel-Jacobi round (role-free rotation, R3/R4; shared-dot split
// rounds, R9). True column = d * w (8 x f16x2); nn tracks true sigma^2.
template<int R>
__device__ __forceinline__ void jround2p(f16x2 (&X)[8], f16x2 (&Y)[8],
                                         f32x2 &nn, f32x2 &d, f32x2 &id) {
  constexpr bool SPLIT = (__builtin_popcount(R) & 1) != 0;
  f32x2 on, od;
  f16x2 oX[8], oY[8];
  if constexpr (SPLIT) {                       // partner has opposite parity:
    on = f32x2{xexch<R>(nn.y), xexch<R>(nn.x)};//  its Y slot is my X matrix
    od = f32x2{xexch<R>(d.y),  xexch<R>(d.x)};
#pragma unroll
    for (int i = 0; i < 8; ++i) oX[i] = i2h(xexch_i<R>(h2i(Y[i])));
#pragma unroll
    for (int i = 0; i < 8; ++i) oY[i] = i2h(xexch_i<R>(h2i(X[i])));
  } else {                                     // same parity: slot pairs slot
    on = f32x2{xexch<R>(nn.x), xexch<R>(nn.y)};
    od = f32x2{xexch<R>(d.x),  xexch<R>(d.y)};
#pragma unroll
    for (int i = 0; i < 8; ++i) oX[i] = i2h(xexch_i<R>(h2i(X[i])));
#pragma unroll
    for (int i = 0; i < 8; ++i) oY[i] = i2h(xexch_i<R>(h2i(Y[i])));
  }

  f32x2 dot;
  if constexpr (SPLIT) {
    float p0 = 0.f, p1 = 0.f, q0 = 0.f, q1 = 0.f;
    p0 = __builtin_amdgcn_fdot2(X[0], oX[0], p0, false);
    p1 = __builtin_amdgcn_fdot2(X[1], oX[1], p1, false);
    q0 = __builtin_amdgcn_fdot2(X[2], oX[2], q0, false);
    q1 = __builtin_amdgcn_fdot2(X[3], oX[3], q1, false);
    p0 = __builtin_amdgcn_fdot2(X[4], oX[4], p0, false);
    p1 = __builtin_amdgcn_fdot2(X[5], oX[5], p1, false);
    q0 = __builtin_amdgcn_fdot2(X[6], oX[6], q0, false);
    q1 = __builtin_amdgcn_fdot2(X[7], oX[7], q1, false);
    const float dx = (p0 + p1) + (q0 + q1);
    dot = f32x2{dx, xexch<R>(dx)};             // partner's dot = my pair's dot
  } else {
    float pa0 = 0.f, pa1 = 0.f, pa2 = 0.f, pa3 = 0.f;
    float pb0 = 0.f, pb1 = 0.f, pb2 = 0.f, pb3 = 0.f;
    pa0 = __builtin_amdgcn_fdot2(X[0], oX[0], pa0, false);
    pa1 = __builtin_amdgcn_fdot2(X[1], oX[1], pa1, false);
    pa2 = __builtin_amdgcn_fdot2(X[2], oX[2], pa2, false);
    pa3 = __builtin_amdgcn_fdot2(X[3], oX[3], pa3, false);
    pb0 = __builtin_amdgcn_fdot2(Y[0], oY[0], pb0, false);
    pb1 = __builtin_amdgcn_fdot2(Y[1], oY[1], pb1, false);
    pb2 = __builtin_amdgcn_fdot2(Y[2], oY[2], pb2, false);
    pb3 = __builtin_amdgcn_fdot2(Y[3], oY[3], pb3, false);
    pa0 = __builtin_amdgcn_fdot2(X[4], oX[4], pa0, false);
    pa1 = __builtin_amdgcn_fdot2(X[5], oX[5], pa1, false);
    pa2 = __builtin_amdgcn_fdot2(X[6], oX[6], pa2, false);
    pa3 = __builtin_amdgcn_fdot2(X[7], oX[7], pa3, false);
    pb0 = __builtin_amdgcn_fdot2(Y[4], oY[4], pb0, false);
    pb1 = __builtin_amdgcn_fdot2(Y[5], oY[5], pb1, false);
    pb2 = __builtin_amdgcn_fdot2(Y[6], oY[6], pb2, false);
    pb3 = __builtin_amdgcn_fdot2(Y[7], oY[7], pb3, false);
    dot = f32x2{(pa0 + pa1) + (pa2 + pa3), (pb0 + pb1) + (pb2 + pb3)};
  }

  const f32x2 dod = d * od;
  const f32x2 apq = dot * dod;
  const f32x2 dl  = on - nn;
  const f32x2 p2  = apq + apq;
  const f32x2 rt  = sqrt2(dl * dl + p2 * p2 + 1e-37f);
  const f32x2 den = dl + cpsgn2(rt, dl);
  const f32x2 t   = p2 * rcp2(den);
  const f32x2 sec = sqrt2(t * t + 1.0f);       // 1/c
  const f32x2 c   = rcp2(sec);
  const f32x2 rc  = -t * (id * od);

  const f16x2 ra = dup_h(rc.x);                // RNE casts
  const f16x2 rb = dup_h(rc.y);
#pragma unroll
  for (int i = 0; i < 8; ++i) X[i] = __builtin_elementwise_fma(ra, oX[i], X[i]);
#pragma unroll
  for (int i = 0; i < 8; ++i) Y[i] = __builtin_elementwise_fma(rb, oY[i], Y[i]);
  d  *= c;
  id *= sec;
  nn  = nn - t * apq;
}

__device__ __forceinline__ void jrounds(f16x2 (&X)[8], f16x2 (&Y)[8],
                                        f32x2 &nn, f32x2 &d, f32x2 &id) {
  jround2p<1>(X, Y, nn, d, id);
  jround2p<2>(X, Y, nn, d, id);
  jround2p<3>(X, Y, nn, d, id);
  jround2p<4>(X, Y, nn, d, id);
  jround2p<5>(X, Y, nn, d, id);
  jround2p<6>(X, Y, nn, d, id);
  jround2p<7>(X, Y, nn, d, id);
  jround2p<8>(X, Y, nn, d, id);
  jround2p<9>(X, Y, nn, d, id);
  jround2p<10>(X, Y, nn, d, id);
  jround2p<11>(X, Y, nn, d, id);
  jround2p<12>(X, Y, nn, d, id);
  jround2p<13>(X, Y, nn, d, id);
  jround2p<14>(X, Y, nn, d, id);
  jround2p<15>(X, Y, nn, d, id);
}

__device__ __forceinline__ void load16(const float* __restrict__ src, float (&a)[16]) {
  const float4* p = (const float4*)src;
  float4 v0 = p[0], v1 = p[1], v2 = p[2], v3 = p[3];
  a[0] = v0.x; a[1] = v0.y; a[2]  = v0.z; a[3]  = v0.w;
  a[4] = v1.x; a[5] = v1.y; a[6]  = v1.z; a[7]  = v1.w;
  a[8] = v2.x; a[9] = v2.y; a[10] = v2.z; a[11] = v2.w;
  a[12] = v3.x; a[13] = v3.y; a[14] = v3.z; a[15] = v3.w;
}

// rank = #(values > own) via 15 xor-exchanges. Stable tie-break.
template<int R>
__device__ __forceinline__ void rankstep(float s2, int lane, int &rank) {
  const float vk = xexch<R>(s2);
  rank += (vk > s2 || (vk == s2 && (lane ^ R) < lane)) ? 1 : 0;
}
__device__ __forceinline__ int rank16(float s2, int lane) {
  int rank = 0;
  rankstep<1>(s2, lane, rank);  rankstep<2>(s2, lane, rank);
  rankstep<3>(s2, lane, rank);  rankstep<4>(s2, lane, rank);
  rankstep<5>(s2, lane, rank);  rankstep<6>(s2, lane, rank);
  rankstep<7>(s2, lane, rank);  rankstep<8>(s2, lane, rank);
  rankstep<9>(s2, lane, rank);  rankstep<10>(s2, lane, rank);
  rankstep<11>(s2, lane, rank); rankstep<12>(s2, lane, rank);
  rankstep<13>(s2, lane, rank); rankstep<14>(s2, lane, rank);
  rankstep<15>(s2, lane, rank);
  return rank;
}

// Descending sort of (u, s2) columns across the 16-lane group.
__device__ __forceinline__ float sort16p(f16x2 (&u)[8], float s2,
                                         const int lane, const int wl) {
  const int rank = rank16(s2, lane);
  const int dst = (((wl & 48) | rank) << 2);
#pragma unroll
  for (int i = 0; i < 8; ++i)
    u[i] = i2h(__builtin_amdgcn_ds_permute(dst, h2i(u[i])));
  return __int_as_float(__builtin_amdgcn_ds_permute(dst, __float_as_int(s2)));
}

template<int CH, int H, int W, int NH, int NW>
__device__ __forceinline__ void svd_body(const float* __restrict__ ref,
                                         const float* __restrict__ dist,
                                         float* __restrict__ dsSum, const int pid) {
  constexpr int P = NH * NW;
  const int tid  = threadIdx.x;
  const int lane = tid & 15;
  const int wl   = tid & 63;
  const int ai   = pid / (CH * P);
  const int rem  = pid - ai * (CH * P);
  const int ch   = rem / P;
  const int pp   = rem - ch * P;
  const int ih   = pp / NW;
  const int iw   = pp - ih * NW;
  // patch matrix M[t][s] = x[ih*4+s, iw*4+t]; lane = column s -> row (ih*4+lane)
  const size_t off = (size_t)(ai * CH + ch) * (H * W) + (size_t)(ih * 4 + lane) * W + iw * 4;

  float tr[16], td[16];
  load16(ref + off, tr);
  load16(dist + off, td);

  float nnr = 0.f, nnd = 0.f;
#pragma unroll
  for (int i = 0; i < 16; ++i) { nnr = fmaf(tr[i], tr[i], nnr); nnd = fmaf(td[i], td[i], nnd); }

  const bool po = (__popc(lane) & 1) != 0;     // parity slot map
  f16x2 X[8], Y[8];
#pragma unroll
  for (int i = 0; i < 8; ++i) {
    const f16x2 hr = f16x2{(_Float16)tr[2 * i], (_Float16)tr[2 * i + 1]};  // RNE
    const f16x2 hd = f16x2{(_Float16)td[2 * i], (_Float16)td[2 * i + 1]};
    X[i] = po ? hd : hr;
    Y[i] = po ? hr : hd;
  }
  f32x2 nn = po ? f32x2{nnd, nnr} : f32x2{nnr, nnd};

  // ROLLED sweep loop (I$-resident body). Unconditional refold leaves d == 1.
#pragma unroll 1
  for (int sw = 0; sw < NSWEEPS; ++sw) {
    f32x2 d  = {1.f, 1.f};
    f32x2 id = {1.f, 1.f};
    jrounds(X, Y, nn, d, id);
    const f16x2 sa = dup_h(d.x), sb = dup_h(d.y);
#pragma unroll
    for (int i = 0; i < 8; ++i) { X[i] *= sa; Y[i] *= sb; }
  }

  // d == 1: sigma^2 = sum(w^2); rsq-fold yields UNIT u columns.
  float r0 = 0.f, r1 = 0.f, q0 = 0.f, q1 = 0.f;
#pragma unroll
  for (int i = 0; i < 8; i += 2) {
    r0 = __builtin_amdgcn_fdot2(X[i],     X[i],     r0, false);
    r1 = __builtin_amdgcn_fdot2(X[i + 1], X[i + 1], r1, false);
    q0 = __builtin_amdgcn_fdot2(Y[i],     Y[i],     q0, false);
    q1 = __builtin_amdgcn_fdot2(Y[i + 1], Y[i + 1], q1, false);
  }
  const float s2X = r0 + r1, s2Y = q0 + q1;
  const f16x2 uX_s = dup_h(__builtin_amdgcn_rsqf(s2X + 1e-30f));
  const f16x2 uY_s = dup_h(__builtin_amdgcn_rsqf(s2Y + 1e-30f));
  f16x2 wr[8], wd[8];                          // unswap slots -> (ref, dist)
#pragma unroll
  for (int i = 0; i < 8; ++i) {
    const f16x2 ux = X[i] * uX_s, uy = Y[i] * uY_s;
    wr[i] = po ? uy : ux;
    wd[i] = po ? ux : uy;
  }
  float s2r = po ? s2Y : s2X;
  float s2d = po ? s2X : s2Y;

  s2r = sort16p(wr, s2r, lane, wl);
  s2d = sort16p(wd, s2d, lane, wl);

  // sum_j (sigma_r - sigma_d)^2 over sorted singular values
  const float sigr = __builtin_amdgcn_sqrtf(s2r);
  const float sigd = __builtin_amdgcn_sqrtf(s2d);
  const float ddv = sigr - sigd;
  float diffs = ddv * ddv;
  diffs += xexch<1>(diffs);
  diffs += xexch<2>(diffs);
  diffs += xexch<4>(diffs);
  diffs += xexch<8>(diffs);

  // u_rd_i = sum_j |u_r[i,j] * u_d[i,j]| : packed products + abs-mask,
  // lane-butterfly on 8 packed regs, sums via fdot2.
  f16x2 prd[8];
#pragma unroll
  for (int i = 0; i < 8; ++i) prd[i] = i2h(h2i(wr[i] * wd[i]) & 0x7FFF7FFF);
#pragma unroll
  for (int i = 0; i < 8; ++i) prd[i] += i2h(xexch_i<1>(h2i(prd[i])));
#pragma unroll
  for (int i = 0; i < 8; ++i) prd[i] += i2h(xexch_i<2>(h2i(prd[i])));
#pragma unroll
  for (int i = 0; i < 8; ++i) prd[i] += i2h(xexch_i<4>(h2i(prd[i])));
#pragma unroll
  for (int i = 0; i < 8; ++i) prd[i] += i2h(xexch_i<8>(h2i(prd[i])));
  const f16x2 one2 = {(_Float16)1.f, (_Float16)1.f};
  float sA0 = 0.f, sA1 = 0.f, sQ0 = 0.f, sQ1 = 0.f;
#pragma unroll
  for (int i = 0; i < 8; i += 2) {
    sA0 = __builtin_amdgcn_fdot2(prd[i],     one2,       sA0, false);
    sA1 = __builtin_amdgcn_fdot2(prd[i + 1], one2,       sA1, false);
    sQ0 = __builtin_amdgcn_fdot2(prd[i],     prd[i],     sQ0, false);
    sQ1 = __builtin_amdgcn_fdot2(prd[i + 1], prd[i + 1], sQ1, false);
  }
  const float sum = sA0 + sA1, sumsq = sQ0 + sQ1;
  const float mean = sum * 0.0625f;
  float var = (sumsq - 16.0f * mean * mean) * (1.0f / 15.0f);  // ddof=1
  var = fmaxf(var, 0.0f);
  const float wt  = __builtin_amdgcn_sqrtf(var) * __builtin_amdgcn_rcpf(mean + 1e-9f);
  const float val = diffs * wt;

  __shared__ float blk;
  if (tid == 0) blk = 0.0f;
  __syncthreads();
  if (lane == 0) atomicAdd(&blk, val);
  __syncthreads();
  if (tid == 0) atomicAdd(&dsSum[ai], blk);   // all groups in a block share 'ai'
}

// SSIM-style global term: per-(a,ch) spatial means of ref & dist.
__device__ __forceinline__ void glb_body(const float* __restrict__ ref,
                                         const float* __restrict__ dist,
                                         float* __restrict__ s1, int bid,
                                         int CH, int HW) {
  const int ai = bid / CH;
  const float4* pr = (const float4*)(ref + (size_t)bid * HW);
  const float4* pd = (const float4*)(dist + (size_t)bid * HW);
  float sr = 0.0f, sd = 0.0f;
  for (int i = threadIdx.x; i < HW / 4; i += 256) {
    const float4 r = pr[i], dv = pd[i];
    sr += (r.x + r.y) + (r.z + r.w);
    sd += (dv.x + dv.y) + (dv.z + dv.w);
  }
#pragma unroll
  for (int st = 32; st >= 1; st >>= 1) { sr += __shfl_xor(sr, st, 64); sd += __shfl_xor(sd, st, 64); }
  __shared__ float bufR[4], bufD[4];
  const int w = threadIdx.x >> 6;
  if ((threadIdx.x & 63) == 0) { bufR[w] = sr; bufD[w] = sd; }
  __syncthreads();
  if (threadIdx.x == 0) {
    const float inv = 1.0f / (float)HW;
    const float ym = (bufR[0] + bufR[1] + bufR[2] + bufR[3]) * inv;  // ref mean
    const float xm = (bufD[0] + bufD[1] + bufD[2] + bufD[3]) * inv;  // dist mean
    const float s1v = (2.0f * xm * ym + 1e-6f) / (xm * xm + ym * ym + 1e-6f);
    atomicAdd(&s1[ai], s1v);
  }
}

#define B3 10816   // 173056/16 feat3 blocks
#define B4 3200    // 51200/16  feat4 blocks
#define G3 1024    // glb3 blocks (4*256)
#define G4 2048    // glb4 blocks (4*512)
#define TOTB (B3 + B4 + G3 + G4)

// One fused grid: [feat3 svd | feat4 svd | glb3 | glb4] + last-block combine.
// Rolled SVD bodies + tiny glb body ~ 18 KB ISA total — fits the 32 KiB I$
// (R7's failure was 60+ KB of unrolled bodies). glb blocks last = short tail.
__global__ __launch_bounds__(256)
void fused_kernel(const float* __restrict__ ref3, const float* __restrict__ dist3,
                  const float* __restrict__ ref4, const float* __restrict__ dist4,
                  float* __restrict__ ws, float* __restrict__ out) {
  const int b = blockIdx.x;
  if (b < B3) {
    svd_body<256, 64, 64, 13, 13>(ref3, dist3, ws + 0, b * 16 + (threadIdx.x >> 4));
  } else if (b < B3 + B4) {
    svd_body<512, 32, 32, 5, 5>(ref4, dist4, ws + 4, (b - B3) * 16 + (threadIdx.x >> 4));
  } else if (b < B3 + B4 + G3) {
    glb_body(ref3, dist3, ws + 8, b - (B3 + B4), 256, 4096);
  } else {
    glb_body(ref4, dist4, ws + 12, b - (B3 + B4 + G3), 512, 1024);
  }

  __threadfence();                             // device-scope: cross-XCD safe
  if (threadIdx.x == 0) {
    const unsigned t = atomicAdd((unsigned*)(ws + 16), 1u);
    if (t == TOTB - 1) {                       // last block: final combine
#pragma unroll
      for (int ai = 0; ai < 4; ++ai) {
        const float ds3 = atomicAdd(&ws[ai],      0.f) * (1.0f / (256.0f * 169.0f));
        const float ds4 = atomicAdd(&ws[4 + ai],  0.f) * (1.0f / (512.0f * 25.0f));
        const float g3  = expf(-2.0f * atomicAdd(&ws[8 + ai],  0.f) * (1.0f / 256.0f));
        const float g4  = expf(-2.0f * atomicAdd(&ws[12 + ai], 0.f) * (1.0f / 512.0f));
        out[ai] = ds3 * g3 + ds4 * g4;
      }
    }
  }
}

extern "C" void kernel_launch(void* const* d_in, const int* in_sizes, int n_in,
                              void* d_out, int out_size, void* d_ws, size_t ws_size,
                              hipStream_t stream) {
  const float* ref3  = (const float*)d_in[0];
  const float* dist3 = (const float*)d_in[1];
  const float* ref4  = (const float*)d_in[2];
  const float* dist4 = (const float*)d_in[3];
  float* ws  = (float*)d_ws;   // [0:4) ds3, [4:8) ds4, [8:12) s13, [12:16) s14, [16] ticket
  float* out = (float*)d_out;

  hipMemsetAsync(ws, 0, 128, stream);
  fused_kernel<<<TOTB, 256, 0, stream>>>(ref3, dist3, ref4, dist4, ws, out);
}

// Round 12
// 594.275 us; speedup vs baseline: 3.0624x; 3.0624x over previous
//
#include <hip/hip_runtime.h>
#include <math.h>

#define NSWEEPS 4

// Packed half2 storage for Jacobi columns. Rotation math f32, packed across
// the two slot matrices as float2.
// R9: parity-slot layout — odd-popcount rounds share the pair dot (bit-neutral).
// R10: ROLLED sweep loop (I$-resident ~7 KB body).
// R11 LESSON (revises R7): per-block __threadfence() (device-scope fence) is
// catastrophic on CDNA4 — it forces L2 writeback/invalidate across the 8
// non-coherent XCD L2s; 17k of them serialized the memory system (VALU 26%).
// So: NO fence/ticket — glb blocks ride the fused grid tail, and the 4-float
// combine stays a separate tiny launch (stream order provides visibility).
typedef _Float16 f16x2 __attribute__((ext_vector_type(2)));
typedef float    f32x2 __attribute__((ext_vector_type(2)));

__device__ __forceinline__ int h2i(f16x2 v) { int r; __builtin_memcpy(&r, &v, 4); return r; }
__device__ __forceinline__ f16x2 i2h(int v) { f16x2 r; __builtin_memcpy(&r, &v, 4); return r; }
__device__ __forceinline__ f16x2 dup_h(float x) { _Float16 h = (_Float16)x; return f16x2{h, h}; }

__device__ __forceinline__ f32x2 rcp2(f32x2 v) {
  return f32x2{__builtin_amdgcn_rcpf(v.x), __builtin_amdgcn_rcpf(v.y)};
}
__device__ __forceinline__ f32x2 sqrt2(f32x2 v) {
  return f32x2{__builtin_amdgcn_sqrtf(v.x), __builtin_amdgcn_sqrtf(v.y)};
}
__device__ __forceinline__ f32x2 cpsgn2(f32x2 m, f32x2 s) {
  return f32x2{copysignf(m.x, s.x), copysignf(m.y, s.y)};  // v_bfi_b32 each
}

// XOR-exchange within 16-lane rows. DPP (VALU pipe) for R in {1,2,3,7,8,15};
// ds_swizzle BitMode (CU-shared LDS pipe) otherwise (pipe balance, R5-R8).
template<int R>
__device__ __forceinline__ int xexch_i(int iv) {
  if constexpr (R == 1)       return __builtin_amdgcn_update_dpp(iv, iv, 0x0B1, 0xF, 0xF, true);
  else if constexpr (R == 2)  return __builtin_amdgcn_update_dpp(iv, iv, 0x04E, 0xF, 0xF, true);
  else if constexpr (R == 3)  return __builtin_amdgcn_update_dpp(iv, iv, 0x01B, 0xF, 0xF, true);
  else if constexpr (R == 7)  return __builtin_amdgcn_update_dpp(iv, iv, 0x141, 0xF, 0xF, true);
  else if constexpr (R == 8)  return __builtin_amdgcn_update_dpp(iv, iv, 0x128, 0xF, 0xF, true);
  else if constexpr (R == 15) return __builtin_amdgcn_update_dpp(iv, iv, 0x140, 0xF, 0xF, true);
  else                        return __builtin_amdgcn_ds_swizzle(iv, (R << 10) | 0x1F);
}
template<int R>
__device__ __forceinline__ float xexch(float v) {
  return __int_as_float(xexch_i<R>(__float_as_int(v)));
}

// One parallel-Jacobi round (role-free rotation, R3/R4; shared-dot split
// rounds, R9). True column = d * w (8 x f16x2); nn tracks true sigma^2.
template<int R>
__device__ __forceinline__ void jround2p(f16x2 (&X)[8], f16x2 (&Y)[8],
                                         f32x2 &nn, f32x2 &d, f32x2 &id) {
  constexpr bool SPLIT = (__builtin_popcount(R) & 1) != 0;
  f32x2 on, od;
  f16x2 oX[8], oY[8];
  if constexpr (SPLIT) {                       // partner has opposite parity:
    on = f32x2{xexch<R>(nn.y), xexch<R>(nn.x)};//  its Y slot is my X matrix
    od = f32x2{xexch<R>(d.y),  xexch<R>(d.x)};
#pragma unroll
    for (int i = 0; i < 8; ++i) oX[i] = i2h(xexch_i<R>(h2i(Y[i])));
#pragma unroll
    for (int i = 0; i < 8; ++i) oY[i] = i2h(xexch_i<R>(h2i(X[i])));
  } else {                                     // same parity: slot pairs slot
    on = f32x2{xexch<R>(nn.x), xexch<R>(nn.y)};
    od = f32x2{xexch<R>(d.x),  xexch<R>(d.y)};
#pragma unroll
    for (int i = 0; i < 8; ++i) oX[i] = i2h(xexch_i<R>(h2i(X[i])));
#pragma unroll
    for (int i = 0; i < 8; ++i) oY[i] = i2h(xexch_i<R>(h2i(Y[i])));
  }

  f32x2 dot;
  if constexpr (SPLIT) {
    float p0 = 0.f, p1 = 0.f, q0 = 0.f, q1 = 0.f;
    p0 = __builtin_amdgcn_fdot2(X[0], oX[0], p0, false);
    p1 = __builtin_amdgcn_fdot2(X[1], oX[1], p1, false);
    q0 = __builtin_amdgcn_fdot2(X[2], oX[2], q0, false);
    q1 = __builtin_amdgcn_fdot2(X[3], oX[3], q1, false);
    p0 = __builtin_amdgcn_fdot2(X[4], oX[4], p0, false);
    p1 = __builtin_amdgcn_fdot2(X[5], oX[5], p1, false);
    q0 = __builtin_amdgcn_fdot2(X[6], oX[6], q0, false);
    q1 = __builtin_amdgcn_fdot2(X[7], oX[7], q1, false);
    const float dx = (p0 + p1) + (q0 + q1);
    dot = f32x2{dx, xexch<R>(dx)};             // partner's dot = my pair's dot
  } else {
    float pa0 = 0.f, pa1 = 0.f, pa2 = 0.f, pa3 = 0.f;
    float pb0 = 0.f, pb1 = 0.f, pb2 = 0.f, pb3 = 0.f;
    pa0 = __builtin_amdgcn_fdot2(X[0], oX[0], pa0, false);
    pa1 = __builtin_amdgcn_fdot2(X[1], oX[1], pa1, false);
    pa2 = __builtin_amdgcn_fdot2(X[2], oX[2], pa2, false);
    pa3 = __builtin_amdgcn_fdot2(X[3], oX[3], pa3, false);
    pb0 = __builtin_amdgcn_fdot2(Y[0], oY[0], pb0, false);
    pb1 = __builtin_amdgcn_fdot2(Y[1], oY[1], pb1, false);
    pb2 = __builtin_amdgcn_fdot2(Y[2], oY[2], pb2, false);
    pb3 = __builtin_amdgcn_fdot2(Y[3], oY[3], pb3, false);
    pa0 = __builtin_amdgcn_fdot2(X[4], oX[4], pa0, false);
    pa1 = __builtin_amdgcn_fdot2(X[5], oX[5], pa1, false);
    pa2 = __builtin_amdgcn_fdot2(X[6], oX[6], pa2, false);
    pa3 = __builtin_amdgcn_fdot2(X[7], oX[7], pa3, false);
    pb0 = __builtin_amdgcn_fdot2(Y[4], oY[4], pb0, false);
    pb1 = __builtin_amdgcn_fdot2(Y[5], oY[5], pb1, false);
    pb2 = __builtin_amdgcn_fdot2(Y[6], oY[6], pb2, false);
    pb3 = __builtin_amdgcn_fdot2(Y[7], oY[7], pb3, false);
    dot = f32x2{(pa0 + pa1) + (pa2 + pa3), (pb0 + pb1) + (pb2 + pb3)};
  }

  const f32x2 dod = d * od;
  const f32x2 apq = dot * dod;
  const f32x2 dl  = on - nn;
  const f32x2 p2  = apq + apq;
  const f32x2 rt  = sqrt2(dl * dl + p2 * p2 + 1e-37f);
  const f32x2 den = dl + cpsgn2(rt, dl);
  const f32x2 t   = p2 * rcp2(den);
  const f32x2 sec = sqrt2(t * t + 1.0f);       // 1/c
  const f32x2 c   = rcp2(sec);
  const f32x2 rc  = -t * (id * od);

  const f16x2 ra = dup_h(rc.x);                // RNE casts
  const f16x2 rb = dup_h(rc.y);
#pragma unroll
  for (int i = 0; i < 8; ++i) X[i] = __builtin_elementwise_fma(ra, oX[i], X[i]);
#pragma unroll
  for (int i = 0; i < 8; ++i) Y[i] = __builtin_elementwise_fma(rb, oY[i], Y[i]);
  d  *= c;
  id *= sec;
  nn  = nn - t * apq;
}

__device__ __forceinline__ void jrounds(f16x2 (&X)[8], f16x2 (&Y)[8],
                                        f32x2 &nn, f32x2 &d, f32x2 &id) {
  jround2p<1>(X, Y, nn, d, id);
  jround2p<2>(X, Y, nn, d, id);
  jround2p<3>(X, Y, nn, d, id);
  jround2p<4>(X, Y, nn, d, id);
  jround2p<5>(X, Y, nn, d, id);
  jround2p<6>(X, Y, nn, d, id);
  jround2p<7>(X, Y, nn, d, id);
  jround2p<8>(X, Y, nn, d, id);
  jround2p<9>(X, Y, nn, d, id);
  jround2p<10>(X, Y, nn, d, id);
  jround2p<11>(X, Y, nn, d, id);
  jround2p<12>(X, Y, nn, d, id);
  jround2p<13>(X, Y, nn, d, id);
  jround2p<14>(X, Y, nn, d, id);
  jround2p<15>(X, Y, nn, d, id);
}

__device__ __forceinline__ void load16(const float* __restrict__ src, float (&a)[16]) {
  const float4* p = (const float4*)src;
  float4 v0 = p[0], v1 = p[1], v2 = p[2], v3 = p[3];
  a[0] = v0.x; a[1] = v0.y; a[2]  = v0.z; a[3]  = v0.w;
  a[4] = v1.x; a[5] = v1.y; a[6]  = v1.z; a[7]  = v1.w;
  a[8] = v2.x; a[9] = v2.y; a[10] = v2.z; a[11] = v2.w;
  a[12] = v3.x; a[13] = v3.y; a[14] = v3.z; a[15] = v3.w;
}

// rank = #(values > own) via 15 xor-exchanges. Stable tie-break.
template<int R>
__device__ __forceinline__ void rankstep(float s2, int lane, int &rank) {
  const float vk = xexch<R>(s2);
  rank += (vk > s2 || (vk == s2 && (lane ^ R) < lane)) ? 1 : 0;
}
__device__ __forceinline__ int rank16(float s2, int lane) {
  int rank = 0;
  rankstep<1>(s2, lane, rank);  rankstep<2>(s2, lane, rank);
  rankstep<3>(s2, lane, rank);  rankstep<4>(s2, lane, rank);
  rankstep<5>(s2, lane, rank);  rankstep<6>(s2, lane, rank);
  rankstep<7>(s2, lane, rank);  rankstep<8>(s2, lane, rank);
  rankstep<9>(s2, lane, rank);  rankstep<10>(s2, lane, rank);
  rankstep<11>(s2, lane, rank); rankstep<12>(s2, lane, rank);
  rankstep<13>(s2, lane, rank); rankstep<14>(s2, lane, rank);
  rankstep<15>(s2, lane, rank);
  return rank;
}

// Descending sort of (u, s2) columns across the 16-lane group.
__device__ __forceinline__ float sort16p(f16x2 (&u)[8], float s2,
                                         const int lane, const int wl) {
  const int rank = rank16(s2, lane);
  const int dst = (((wl & 48) | rank) << 2);
#pragma unroll
  for (int i = 0; i < 8; ++i)
    u[i] = i2h(__builtin_amdgcn_ds_permute(dst, h2i(u[i])));
  return __int_as_float(__builtin_amdgcn_ds_permute(dst, __float_as_int(s2)));
}

template<int CH, int H, int W, int NH, int NW>
__device__ __forceinline__ void svd_body(const float* __restrict__ ref,
                                         const float* __restrict__ dist,
                                         float* __restrict__ dsSum, const int pid) {
  constexpr int P = NH * NW;
  const int tid  = threadIdx.x;
  const int lane = tid & 15;
  const int wl   = tid & 63;
  const int ai   = pid / (CH * P);
  const int rem  = pid - ai * (CH * P);
  const int ch   = rem / P;
  const int pp   = rem - ch * P;
  const int ih   = pp / NW;
  const int iw   = pp - ih * NW;
  // patch matrix M[t][s] = x[ih*4+s, iw*4+t]; lane = column s -> row (ih*4+lane)
  const size_t off = (size_t)(ai * CH + ch) * (H * W) + (size_t)(ih * 4 + lane) * W + iw * 4;

  float tr[16], td[16];
  load16(ref + off, tr);
  load16(dist + off, td);

  float nnr = 0.f, nnd = 0.f;
#pragma unroll
  for (int i = 0; i < 16; ++i) { nnr = fmaf(tr[i], tr[i], nnr); nnd = fmaf(td[i], td[i], nnd); }

  const bool po = (__popc(lane) & 1) != 0;     // parity slot map
  f16x2 X[8], Y[8];
#pragma unroll
  for (int i = 0; i < 8; ++i) {
    const f16x2 hr = f16x2{(_Float16)tr[2 * i], (_Float16)tr[2 * i + 1]};  // RNE
    const f16x2 hd = f16x2{(_Float16)td[2 * i], (_Float16)td[2 * i + 1]};
    X[i] = po ? hd : hr;
    Y[i] = po ? hr : hd;
  }
  f32x2 nn = po ? f32x2{nnd, nnr} : f32x2{nnr, nnd};

  // ROLLED sweep loop (I$-resident body). Unconditional refold leaves d == 1.
#pragma unroll 1
  for (int sw = 0; sw < NSWEEPS; ++sw) {
    f32x2 d  = {1.f, 1.f};
    f32x2 id = {1.f, 1.f};
    jrounds(X, Y, nn, d, id);
    const f16x2 sa = dup_h(d.x), sb = dup_h(d.y);
#pragma unroll
    for (int i = 0; i < 8; ++i) { X[i] *= sa; Y[i] *= sb; }
  }

  // d == 1: sigma^2 = sum(w^2); rsq-fold yields UNIT u columns.
  float r0 = 0.f, r1 = 0.f, q0 = 0.f, q1 = 0.f;
#pragma unroll
  for (int i = 0; i < 8; i += 2) {
    r0 = __builtin_amdgcn_fdot2(X[i],     X[i],     r0, false);
    r1 = __builtin_amdgcn_fdot2(X[i + 1], X[i + 1], r1, false);
    q0 = __builtin_amdgcn_fdot2(Y[i],     Y[i],     q0, false);
    q1 = __builtin_amdgcn_fdot2(Y[i + 1], Y[i + 1], q1, false);
  }
  const float s2X = r0 + r1, s2Y = q0 + q1;
  const f16x2 uX_s = dup_h(__builtin_amdgcn_rsqf(s2X + 1e-30f));
  const f16x2 uY_s = dup_h(__builtin_amdgcn_rsqf(s2Y + 1e-30f));
  f16x2 wr[8], wd[8];                          // unswap slots -> (ref, dist)
#pragma unroll
  for (int i = 0; i < 8; ++i) {
    const f16x2 ux = X[i] * uX_s, uy = Y[i] * uY_s;
    wr[i] = po ? uy : ux;
    wd[i] = po ? ux : uy;
  }
  float s2r = po ? s2Y : s2X;
  float s2d = po ? s2X : s2Y;

  s2r = sort16p(wr, s2r, lane, wl);
  s2d = sort16p(wd, s2d, lane, wl);

  // sum_j (sigma_r - sigma_d)^2 over sorted singular values
  const float sigr = __builtin_amdgcn_sqrtf(s2r);
  const float sigd = __builtin_amdgcn_sqrtf(s2d);
  const float ddv = sigr - sigd;
  float diffs = ddv * ddv;
  diffs += xexch<1>(diffs);
  diffs += xexch<2>(diffs);
  diffs += xexch<4>(diffs);
  diffs += xexch<8>(diffs);

  // u_rd_i = sum_j |u_r[i,j] * u_d[i,j]| : packed products + abs-mask,
  // lane-butterfly on 8 packed regs, sums via fdot2.
  f16x2 prd[8];
#pragma unroll
  for (int i = 0; i < 8; ++i) prd[i] = i2h(h2i(wr[i] * wd[i]) & 0x7FFF7FFF);
#pragma unroll
  for (int i = 0; i < 8; ++i) prd[i] += i2h(xexch_i<1>(h2i(prd[i])));
#pragma unroll
  for (int i = 0; i < 8; ++i) prd[i] += i2h(xexch_i<2>(h2i(prd[i])));
#pragma unroll
  for (int i = 0; i < 8; ++i) prd[i] += i2h(xexch_i<4>(h2i(prd[i])));
#pragma unroll
  for (int i = 0; i < 8; ++i) prd[i] += i2h(xexch_i<8>(h2i(prd[i])));
  const f16x2 one2 = {(_Float16)1.f, (_Float16)1.f};
  float sA0 = 0.f, sA1 = 0.f, sQ0 = 0.f, sQ1 = 0.f;
#pragma unroll
  for (int i = 0; i < 8; i += 2) {
    sA0 = __builtin_amdgcn_fdot2(prd[i],     one2,       sA0, false);
    sA1 = __builtin_amdgcn_fdot2(prd[i + 1], one2,       sA1, false);
    sQ0 = __builtin_amdgcn_fdot2(prd[i],     prd[i],     sQ0, false);
    sQ1 = __builtin_amdgcn_fdot2(prd[i + 1], prd[i + 1], sQ1, false);
  }
  const float sum = sA0 + sA1, sumsq = sQ0 + sQ1;
  const float mean = sum * 0.0625f;
  float var = (sumsq - 16.0f * mean * mean) * (1.0f / 15.0f);  // ddof=1
  var = fmaxf(var, 0.0f);
  const float wt  = __builtin_amdgcn_sqrtf(var) * __builtin_amdgcn_rcpf(mean + 1e-9f);
  const float val = diffs * wt;

  __shared__ float blk;
  if (tid == 0) blk = 0.0f;
  __syncthreads();
  if (lane == 0) atomicAdd(&blk, val);
  __syncthreads();
  if (tid == 0) atomicAdd(&dsSum[ai], blk);   // all groups in a block share 'ai'
}

// SSIM-style global term: per-(a,ch) spatial means of ref & dist.
__device__ __forceinline__ void glb_body(const float* __restrict__ ref,
                                         const float* __restrict__ dist,
                                         float* __restrict__ s1, int bid,
                                         int CH, int HW) {
  const int ai = bid / CH;
  const float4* pr = (const float4*)(ref + (size_t)bid * HW);
  const float4* pd = (const float4*)(dist + (size_t)bid * HW);
  float sr = 0.0f, sd = 0.0f;
  for (int i = threadIdx.x; i < HW / 4; i += 256) {
    const float4 r = pr[i], dv = pd[i];
    sr += (r.x + r.y) + (r.z + r.w);
    sd += (dv.x + dv.y) + (dv.z + dv.w);
  }
#pragma unroll
  for (int st = 32; st >= 1; st >>= 1) { sr += __shfl_xor(sr, st, 64); sd += __shfl_xor(sd, st, 64); }
  __shared__ float bufR[4], bufD[4];
  const int w = threadIdx.x >> 6;
  if ((threadIdx.x & 63) == 0) { bufR[w] = sr; bufD[w] = sd; }
  __syncthreads();
  if (threadIdx.x == 0) {
    const float inv = 1.0f / (float)HW;
    const float ym = (bufR[0] + bufR[1] + bufR[2] + bufR[3]) * inv;  // ref mean
    const float xm = (bufD[0] + bufD[1] + bufD[2] + bufD[3]) * inv;  // dist mean
    const float s1v = (2.0f * xm * ym + 1e-6f) / (xm * xm + ym * ym + 1e-6f);
    atomicAdd(&s1[ai], s1v);
  }
}

#define B3 10816   // 173056/16 feat3 blocks
#define B4 3200    // 51200/16  feat4 blocks
#define G3 1024    // glb3 blocks (4*256)
#define G4 2048    // glb4 blocks (4*512)
#define TOTB (B3 + B4 + G3 + G4)

// Fused grid: [feat3 svd | feat4 svd | glb3 | glb4]. NO fence, NO ticket —
// plain device atomicAdds into ws; the separate final_kernel launch (stream
// order) reads them. glb blocks last = they backfill the SVD drain tail.
__global__ __launch_bounds__(256)
void fused_kernel(const float* __restrict__ ref3, const float* __restrict__ dist3,
                  const float* __restrict__ ref4, const float* __restrict__ dist4,
                  float* __restrict__ ws) {
  const int b = blockIdx.x;
  if (b < B3) {
    svd_body<256, 64, 64, 13, 13>(ref3, dist3, ws + 0, b * 16 + (threadIdx.x >> 4));
  } else if (b < B3 + B4) {
    svd_body<512, 32, 32, 5, 5>(ref4, dist4, ws + 4, (b - B3) * 16 + (threadIdx.x >> 4));
  } else if (b < B3 + B4 + G3) {
    glb_body(ref3, dist3, ws + 8, b - (B3 + B4), 256, 4096);
  } else {
    glb_body(ref4, dist4, ws + 12, b - (B3 + B4 + G3), 512, 1024);
  }
}

__global__ void final_kernel(const float* __restrict__ ws, float* __restrict__ out) {
  const int ai = threadIdx.x;
  if (ai < 4) {
    const float ds3 = ws[ai]      * (1.0f / (256.0f * 169.0f));
    const float ds4 = ws[4 + ai]  * (1.0f / (512.0f * 25.0f));
    const float g3  = expf(-2.0f * ws[8 + ai]  * (1.0f / 256.0f));
    const float g4  = expf(-2.0f * ws[12 + ai] * (1.0f / 512.0f));
    out[ai] = ds3 * g3 + ds4 * g4;
  }
}

extern "C" void kernel_launch(void* const* d_in, const int* in_sizes, int n_in,
                              void* d_out, int out_size, void* d_ws, size_t ws_size,
                              hipStream_t stream) {
  const float* ref3  = (const float*)d_in[0];
  const float* dist3 = (const float*)d_in[1];
  const float* ref4  = (const float*)d_in[2];
  const float* dist4 = (const float*)d_in[3];
  float* ws  = (float*)d_ws;   // [0:4) ds3, [4:8) ds4, [8:12) s13, [12:16) s14
  float* out = (float*)d_out;

  hipMemsetAsync(ws, 0, 16 * sizeof(float), stream);
  fused_kernel<<<TOTB, 256, 0, stream>>>(ref3, dist3, ref4, dist4, ws);
  final_kernel<<<1, 64, 0, stream>>>(ws, out);
}